// Round 5
// baseline (340.088 us; speedup 1.0000x reference)
//
#include <hip/hip_runtime.h>

#define N_NODES 50000
#define N_EDGES 800000
#define IN_F 256
#define OUT_F 64

#define NB 196          // scan blocks: 196*256 = 50176 >= 50000
#define GEMM_BLOCKS 782 // 782*8 waves = 6256 >= 6250 node-groups of 8
#define FILL_BLOCKS 1563 // 1563*512 = 800256 >= 800000

// ---------------- fused: GEMM (h = x @ W)  ||  fill (CSR permute) ----------
// GEMM blocks: 512 thr = 8 waves; wave = 8 nodes, lane = feature.
//   W[k*64+f]: per-lane coalesced 256B loads, L1/L2-resident, reused x8 nodes.
//   x[n][k..k+3]: wave-uniform broadcast float4 loads. All VMEM (vmcnt) ->
//   compiler pipelines; no LDS, no barriers, no lgkmcnt coupling.
// Fill blocks: scatter edges into dst-sorted order (runs concurrently;
//   scatter/L2-bound, overlaps the FMA-bound gemm blocks).
__global__ __launch_bounds__(512) void gc_gemm_fill(
    const float* __restrict__ x, const float* __restrict__ W,
    float* __restrict__ h,
    const int* __restrict__ src, const int* __restrict__ dst,
    const float* __restrict__ ew,
    int* __restrict__ cursor, int2* __restrict__ sorted) {
    if (blockIdx.x < GEMM_BLOCKS) {
        const int t = threadIdx.x;
        const int f = t & 63;
        const int gw = blockIdx.x * 8 + (t >> 6);
        if (gw >= N_NODES / 8) return;  // 50000/8 = 6250 full waves
        const int n0 = gw * 8;

        const float* __restrict__ Wf = W + f;
        const float* __restrict__ xr = x + (size_t)n0 * IN_F;

        float acc[8];
#pragma unroll
        for (int j = 0; j < 8; ++j) acc[j] = 0.f;

#pragma unroll 2
        for (int k = 0; k < IN_F; k += 4) {
            const float w0 = Wf[(k + 0) * OUT_F];
            const float w1 = Wf[(k + 1) * OUT_F];
            const float w2 = Wf[(k + 2) * OUT_F];
            const float w3 = Wf[(k + 3) * OUT_F];
#pragma unroll
            for (int j = 0; j < 8; ++j) {
                const float4 xv = *(const float4*)(xr + j * IN_F + k);
                acc[j] += xv.x * w0 + xv.y * w1 + xv.z * w2 + xv.w * w3;
            }
        }

#pragma unroll
        for (int j = 0; j < 8; ++j)
            h[(size_t)(n0 + j) * OUT_F + f] = acc[j];
    } else {
        const int i = (blockIdx.x - GEMM_BLOCKS) * 512 + threadIdx.x;
        if (i < N_EDGES) {
            const int d = dst[i];
            const int pos = atomicAdd(&cursor[d], 1);
            sorted[pos] = make_int2(src[i], __float_as_int(ew[i]));
        }
    }
}

// ---------------- CSR build ----------------
__global__ __launch_bounds__(256) void gc_hist(const int* __restrict__ dst,
                                               int* __restrict__ cnt) {
    const int i = blockIdx.x * blockDim.x + threadIdx.x;
    if (i < N_EDGES) atomicAdd(&cnt[dst[i]], 1);
}

// A: per-block sum of 256 counts -> bsum[block]
__global__ __launch_bounds__(256) void gc_scan_reduce(const int* __restrict__ cnt,
                                                      int* __restrict__ bsum) {
    __shared__ int sd[4];
    const int i = blockIdx.x * 256 + threadIdx.x;
    int v = (i < N_NODES) ? cnt[i] : 0;
#pragma unroll
    for (int d = 32; d > 0; d >>= 1) v += __shfl_down(v, d, 64);
    if ((threadIdx.x & 63) == 0) sd[threadIdx.x >> 6] = v;
    __syncthreads();
    if (threadIdx.x == 0) bsum[blockIdx.x] = sd[0] + sd[1] + sd[2] + sd[3];
}

// B: exclusive scan of NB block sums -> bpre; also writes offs[N_NODES]=total
__global__ __launch_bounds__(256) void gc_scan_tops(const int* __restrict__ bsum,
                                                    int* __restrict__ bpre,
                                                    int* __restrict__ offs) {
    __shared__ int sd[256];
    const int t = threadIdx.x;
    const int v = (t < NB) ? bsum[t] : 0;
    sd[t] = v;
    __syncthreads();
#pragma unroll
    for (int d = 1; d < 256; d <<= 1) {
        const int u = (t >= d) ? sd[t - d] : 0;
        __syncthreads();
        sd[t] += u;
        __syncthreads();
    }
    if (t < NB) bpre[t] = sd[t] - v;  // exclusive
    if (t == NB - 1) offs[N_NODES] = sd[t];
}

// C: block-local exclusive scan + base -> offs, cursor
__global__ __launch_bounds__(256) void gc_scan_down(const int* __restrict__ cnt,
                                                    const int* __restrict__ bpre,
                                                    int* __restrict__ offs,
                                                    int* __restrict__ cursor) {
    __shared__ int sd[256];
    const int t = threadIdx.x;
    const int i = blockIdx.x * 256 + t;
    const int v = (i < N_NODES) ? cnt[i] : 0;
    sd[t] = v;
    __syncthreads();
#pragma unroll
    for (int d = 1; d < 256; d <<= 1) {
        const int u = (t >= d) ? sd[t - d] : 0;
        __syncthreads();
        sd[t] += u;
        __syncthreads();
    }
    if (i < N_NODES) {
        const int off = bpre[blockIdx.x] + sd[t] - v;
        offs[i] = off;
        cursor[i] = off;
    }
}

// ---------------- gather: out[d] = bias + sum w*h[src] ----------------
__global__ __launch_bounds__(256) void gc_gather(const float* __restrict__ h,
                                                 const int2* __restrict__ sorted,
                                                 const int* __restrict__ offs,
                                                 const float* __restrict__ bias,
                                                 float* __restrict__ out) {
    const int gw = (blockIdx.x * blockDim.x + threadIdx.x) >> 6;
    const int f = threadIdx.x & 63;
    if (gw >= N_NODES) return;
    const int beg = offs[gw];
    const int end = offs[gw + 1];
    float acc = bias[f];
    int i = beg;
    for (; i + 4 <= end; i += 4) {
        const int2 e0 = sorted[i + 0];
        const int2 e1 = sorted[i + 1];
        const int2 e2 = sorted[i + 2];
        const int2 e3 = sorted[i + 3];
        const float h0 = h[(size_t)e0.x * OUT_F + f];
        const float h1 = h[(size_t)e1.x * OUT_F + f];
        const float h2 = h[(size_t)e2.x * OUT_F + f];
        const float h3 = h[(size_t)e3.x * OUT_F + f];
        acc += __int_as_float(e0.y) * h0;
        acc += __int_as_float(e1.y) * h1;
        acc += __int_as_float(e2.y) * h2;
        acc += __int_as_float(e3.y) * h3;
    }
    for (; i < end; ++i) {
        const int2 e0 = sorted[i];
        acc += __int_as_float(e0.y) * h[(size_t)e0.x * OUT_F + f];
    }
    out[(size_t)gw * OUT_F + f] = acc;
}

extern "C" void kernel_launch(void* const* d_in, const int* in_sizes, int n_in,
                              void* d_out, int out_size, void* d_ws, size_t ws_size,
                              hipStream_t stream) {
    const float* x    = (const float*)d_in[0];
    const float* W    = (const float*)d_in[1];
    const float* bias = (const float*)d_in[2];
    const float* ew   = (const float*)d_in[3];
    const int* src    = (const int*)d_in[4];
    const int* dst    = (const int*)d_in[5];
    float* out = (float*)d_out;

    // workspace layout (16B-aligned)
    char* ws = (char*)d_ws;
    float* h      = (float*)ws;                       // 12,800,000 B
    int*   cnt    = (int*)(ws + 12800000);            // 200,000 B
    int*   offs   = (int*)(ws + 13000000);            // 200,004 B (50001)
    int*   cursor = (int*)(ws + 13200016);            // 200,000 B
    int*   bsum   = (int*)(ws + 13400016);            // 784 B
    int*   bpre   = (int*)(ws + 13400800);            // 784 B
    int2*  sorted = (int2*)(ws + 13401600);           // 6,400,000 B (end ~19.8 MB)

    hipMemsetAsync(cnt, 0, (size_t)N_NODES * sizeof(int), stream);

    gc_hist<<<(N_EDGES + 255) / 256, 256, 0, stream>>>(dst, cnt);
    gc_scan_reduce<<<NB, 256, 0, stream>>>(cnt, bsum);
    gc_scan_tops<<<1, 256, 0, stream>>>(bsum, bpre, offs);
    gc_scan_down<<<NB, 256, 0, stream>>>(cnt, bpre, offs, cursor);

    // gemm (independent) fused with fill (depends on scan): overlap FMA-bound
    // gemm blocks with scatter-bound fill blocks in one dispatch.
    gc_gemm_fill<<<GEMM_BLOCKS + FILL_BLOCKS, 512, 0, stream>>>(
        x, W, h, src, dst, ew, cursor, sorted);

    gc_gather<<<(N_NODES * 64 + 255) / 256, 256, 0, stream>>>(h, sorted, offs, bias, out);
}

// Round 6
// 253.039 us; speedup vs baseline: 1.3440x; 1.3440x over previous
//
#include <hip/hip_runtime.h>

#define N_NODES 50000
#define N_EDGES 800000
#define IN_F 256
#define OUT_F 64

#define TNODE 32   // nodes per gemm block (8 per wave x 4 waves)
#define NCH 4      // dst chains per wave in gather

// ---------------- GEMM: h = x @ W (R3 version, measured 60us) ----------------
__global__ __launch_bounds__(256) void gc_gemm(const float* __restrict__ x,
                                               const float* __restrict__ W,
                                               float* __restrict__ h) {
    __shared__ float xs[TNODE * IN_F];  // 32 KB
    const int t = threadIdx.x;
    const int nbase = blockIdx.x * TNODE;
    const int nvalid = min(TNODE, N_NODES - nbase);

    {
        const float4* __restrict__ xg = (const float4*)(x + (size_t)nbase * IN_F);
        float4* __restrict__ xs4 = (float4*)xs;
        const int lim4 = nvalid * (IN_F / 4);
#pragma unroll
        for (int i = 0; i < TNODE * IN_F / 4 / 256; ++i) {
            const int idx = t + i * 256;
            if (idx < lim4) xs4[idx] = xg[idx];
        }
    }
    __syncthreads();

    const int wave = t >> 6;
    const int f = t & 63;
    const int n0 = wave * 8;

    float acc[8];
#pragma unroll
    for (int j = 0; j < 8; ++j) acc[j] = 0.f;

#pragma unroll 2
    for (int k = 0; k < IN_F; k += 4) {
        const float w0 = W[(k + 0) * OUT_F + f];
        const float w1 = W[(k + 1) * OUT_F + f];
        const float w2 = W[(k + 2) * OUT_F + f];
        const float w3 = W[(k + 3) * OUT_F + f];
#pragma unroll
        for (int j = 0; j < 8; ++j) {
            const float4 xv = *(const float4*)&xs[(n0 + j) * IN_F + k];
            acc[j] += xv.x * w0 + xv.y * w1 + xv.z * w2 + xv.w * w3;
        }
    }

#pragma unroll
    for (int j = 0; j < 8; ++j) {
        const int n = nbase + n0 + j;
        if (n < N_NODES) h[(size_t)n * OUT_F + f] = acc[j];
    }
}

// ---------------- linked-list adjacency build ----------------
// next[] writes are coalesced (edge-indexed); only 4B head exchanges scatter.
__global__ __launch_bounds__(256) void gc_link(const int* __restrict__ dst,
                                               int* __restrict__ head,
                                               int* __restrict__ nxt) {
    const int i = blockIdx.x * blockDim.x + threadIdx.x;
    if (i < N_EDGES) {
        const int old = atomicExch(&head[dst[i]], i);
        nxt[i] = old;
    }
}

// ---------------- gather: out[d] = bias + sum w*h[src] via chain walk -------
// One wave handles NCH dst chains (lane = feature). Chain state e[j] is
// wave-uniform -> uniform branches; 4 independent chains hide pointer-chase
// latency; h gathers are coalesced 256B reads.
__global__ __launch_bounds__(256) void gc_gather(const float* __restrict__ h,
                                                 const int* __restrict__ src,
                                                 const float* __restrict__ ew,
                                                 const int* __restrict__ head,
                                                 const int* __restrict__ nxt,
                                                 const float* __restrict__ bias,
                                                 float* __restrict__ out) {
    const int gw = (blockIdx.x * blockDim.x + threadIdx.x) >> 6;
    const int f = threadIdx.x & 63;
    const int d0 = gw * NCH;
    if (d0 >= N_NODES) return;

    const float b = bias[f];
    float acc[NCH];
    int e[NCH];
#pragma unroll
    for (int j = 0; j < NCH; ++j) {
        acc[j] = b;
        e[j] = (d0 + j < N_NODES) ? head[d0 + j] : -1;
    }

    for (;;) {
        bool any = false;
        int s[NCH], en[NCH];
        float w[NCH];
        // issue all chain loads first (independent across j)
#pragma unroll
        for (int j = 0; j < NCH; ++j) {
            if (e[j] >= 0) {
                s[j] = src[e[j]];
                w[j] = ew[e[j]];
                en[j] = nxt[e[j]];
                any = true;
            }
        }
        if (!any) break;
#pragma unroll
        for (int j = 0; j < NCH; ++j) {
            if (e[j] >= 0) {
                acc[j] += w[j] * h[(size_t)s[j] * OUT_F + f];
                e[j] = en[j];
            }
        }
    }

#pragma unroll
    for (int j = 0; j < NCH; ++j) {
        const int d = d0 + j;
        if (d < N_NODES) out[(size_t)d * OUT_F + f] = acc[j];
    }
}

extern "C" void kernel_launch(void* const* d_in, const int* in_sizes, int n_in,
                              void* d_out, int out_size, void* d_ws, size_t ws_size,
                              hipStream_t stream) {
    const float* x    = (const float*)d_in[0];
    const float* W    = (const float*)d_in[1];
    const float* bias = (const float*)d_in[2];
    const float* ew   = (const float*)d_in[3];
    const int* src    = (const int*)d_in[4];
    const int* dst    = (const int*)d_in[5];
    float* out = (float*)d_out;

    // workspace layout (16B-aligned)
    char* ws = (char*)d_ws;
    float* h    = (float*)ws;                 // 12,800,000 B
    int*   head = (int*)(ws + 12800000);      // 200,000 B
    int*   nxt  = (int*)(ws + 13000000);      // 3,200,000 B (end ~16.2 MB)

    // head = -1 (0xFFFFFFFF)
    hipMemsetAsync(head, 0xFF, (size_t)N_NODES * sizeof(int), stream);

    gc_link<<<(N_EDGES + 255) / 256, 256, 0, stream>>>(dst, head, nxt);

    gc_gemm<<<(N_NODES + TNODE - 1) / TNODE, 256, 0, stream>>>(x, W, h);

    // 4 waves/block x NCH chains = 16 dsts per block
    gc_gather<<<(N_NODES + 4 * NCH - 1) / (4 * NCH), 256, 0, stream>>>(
        h, src, ew, head, nxt, bias, out);
}